// Round 5
// baseline (4989.391 us; speedup 1.0000x reference)
//
#include <hip/hip_runtime.h>
#include <stdint.h>

namespace {

constexpr int B_   = 512;
constexpr int T_   = 512;
constexpr int IN_  = 6;
constexpr int H_   = 64;
constexpr int HH_  = 128;
constexpr int OUT_ = 8;

typedef _Float16 f16x2 __attribute__((ext_vector_type(2)));

__device__ __forceinline__ float dot2f(uint32_t w, uint32_t z, float acc) {
    return __builtin_amdgcn_fdot2(__builtin_bit_cast(f16x2, w),
                                  __builtin_bit_cast(f16x2, z), acc, false);
}

__device__ __forceinline__ uint32_t pack2f(float a, float b) {
    f16x2 p;
    p[0] = (_Float16)a;
    p[1] = (_Float16)b;
    return __builtin_bit_cast(uint32_t, p);
}

// pair sum (lanes 2c/2c+1) via DPP quad_perm [1,0,3,2] — pure VALU, no LDS pipe.
__device__ __forceinline__ float psum2(float v) {
    int y = __builtin_amdgcn_mov_dpp(__builtin_bit_cast(int, v), 0xB1, 0xF, 0xF, true);
    return v + __builtin_bit_cast(float, y);
}

__device__ __forceinline__ float tanh_fast(float v) {
    float ax = fabsf(v);
    float e  = __expf(2.0f * ax);
    float r  = 1.0f - 2.0f / (e + 1.0f);
    return copysignf(r, v);
}

// One workgroup (256 threads) per batch element.
//   thread t: column c = t>>1, k-half kh = t&1.
//   176 packed-f16-pair weight u32 per thread, all in arch VGPRs
//   (launch_bounds(256,1) -> 512-reg cap; ~220 used -> 2 waves/SIMD, no spill).
__global__ __launch_bounds__(256, 1) void cde_kernel(
    const float* __restrict__ x,
    const float* __restrict__ W_init, const float* __restrict__ b_init,
    const float* __restrict__ W_in,   const float* __restrict__ b_in,
    const float* __restrict__ W_h1,   const float* __restrict__ b_h1,
    const float* __restrict__ W_h2,   const float* __restrict__ b_h2,
    const float* __restrict__ W_out,  const float* __restrict__ b_out,
    const float* __restrict__ W_fin,  const float* __restrict__ b_fin,
    float* __restrict__ out)
{
    const int b  = blockIdx.x;
    const int t  = threadIdx.x;
    const int c  = t >> 1;      // 0..127
    const int kh = t & 1;       // k-half

    __shared__ alignas(16) uint32_t hinu[H_ / 2];    // 64 f16 (vf input h)
    __shared__ alignas(16) uint32_t zAu[HH_ / 2];    // 128 f16 ping
    __shared__ alignas(16) uint32_t zBu[HH_ / 2];    // 128 f16 pong
    __shared__ float pp[H_ * IN_];                   // tanh(A)*dx  (round-3 layout: 0 conflicts)
    __shared__ float dxs[IN_];
    __shared__ float hbuf[H_];

    // ---- register-resident f16 weights (k-half slice) ----
    uint32_t w1[16], w2[32], w3[32], w4[96];
    #pragma unroll
    for (int i = 0; i < 16; ++i) {
        int k = kh * 32 + 2 * i;
        w1[i] = pack2f(W_in[k * HH_ + c], W_in[(k + 1) * HH_ + c]);
    }
    #pragma unroll
    for (int i = 0; i < 32; ++i) {
        int k = kh * 64 + 2 * i;
        w2[i] = pack2f(W_h1[k * HH_ + c], W_h1[(k + 1) * HH_ + c]);
        w3[i] = pack2f(W_h2[k * HH_ + c], W_h2[(k + 1) * HH_ + c]);
    }
    #pragma unroll
    for (int j = 0; j < 3; ++j) {
        const int cc = c + 128 * j;
        #pragma unroll
        for (int i = 0; i < 32; ++i) {
            int k = kh * 64 + 2 * i;
            w4[j * 32 + i] = pack2f(W_out[k * 384 + cc], W_out[(k + 1) * 384 + cc]);
        }
    }
    const float bin_r = b_in[c];
    const float bh1_r = b_h1[c];
    const float bh2_r = b_h2[c];
    const float bo0 = b_out[c], bo1 = b_out[c + 128], bo2 = b_out[c + 256];
    const int   m0 = c % 6, m1 = (c + 128) % 6, m2 = (c + 256) % 6;
    const float bfin_r = (t < OUT_) ? b_fin[t] : 0.0f;

    // W_fin rows in registers (out-stage threads < 64) — LDS version bank-conflicts.
    float wfr[8];
    #pragma unroll
    for (int j = 0; j < 8; ++j)
        wfr[j] = (t < 64) ? W_fin[((t >> 3) * 8 + j) * OUT_ + (t & 7)] : 0.0f;

    const size_t xbase = (size_t)b * T_ * IN_;
    const size_t obase = (size_t)b * T_ * OUT_;

    float xa = 0.f, xb = 0.f;
    if (t < IN_) {
        xa = x[xbase + t];
        xb = x[xbase + IN_ + t];
    }

    // ---- h0 = x[:,0] @ W_init + b_init (wave 0) ----
    float h_reg = 0.f, hacc = 0.f;
    if (t < H_) {
        float s = b_init[t];
        #pragma unroll
        for (int i = 0; i < IN_; ++i) s += x[xbase + i] * W_init[i * H_ + t];
        h_reg = s;
        hbuf[t] = s;
        ((_Float16*)hinu)[t] = (_Float16)s;
    }
    __syncthreads();

    // out for t = 0
    if (t < 64) {
        int o = t & 7, part = t >> 3;
        float s = 0.f;
        #pragma unroll
        for (int j = 0; j < 8; ++j) s += hbuf[part * 8 + j] * wfr[j];
        s += __shfl_xor(s, 8);
        s += __shfl_xor(s, 16);
        s += __shfl_xor(s, 32);
        if (part == 0) out[obase + o] = s + bfin_r;
    }

    for (int step = 0; step < T_ - 1; ++step) {
        // dxs for this step; readers (G4) are >=3 barriers later; previous
        // step's last reader was >=2 barriers earlier.
        if (t < IN_) {
            dxs[t] = xb - xa;
            xa = xb;
            if (step + 2 < T_) xb = x[xbase + (size_t)(step + 2) * IN_ + t];
        }

        #pragma unroll
        for (int s4 = 0; s4 < 4; ++s4) {
            // ---- G1: h(64) -> z1(128) into zA ----
            {
                const uint32_t* hp = hinu + kh * 16;
                uint4 q0 = *reinterpret_cast<const uint4*>(hp);
                uint4 q1 = *reinterpret_cast<const uint4*>(hp + 4);
                uint4 q2 = *reinterpret_cast<const uint4*>(hp + 8);
                uint4 q3 = *reinterpret_cast<const uint4*>(hp + 12);
                float a = 0.f, d = 0.f;
                a = dot2f(w1[0],  q0.x, a); d = dot2f(w1[1],  q0.y, d);
                a = dot2f(w1[2],  q0.z, a); d = dot2f(w1[3],  q0.w, d);
                a = dot2f(w1[4],  q1.x, a); d = dot2f(w1[5],  q1.y, d);
                a = dot2f(w1[6],  q1.z, a); d = dot2f(w1[7],  q1.w, d);
                a = dot2f(w1[8],  q2.x, a); d = dot2f(w1[9],  q2.y, d);
                a = dot2f(w1[10], q2.z, a); d = dot2f(w1[11], q2.w, d);
                a = dot2f(w1[12], q3.x, a); d = dot2f(w1[13], q3.y, d);
                a = dot2f(w1[14], q3.z, a); d = dot2f(w1[15], q3.w, d);
                float z = fmaxf(bin_r + psum2(a + d), 0.f);
                if (kh == 0) ((_Float16*)zAu)[c] = (_Float16)z;
            }
            __syncthreads();

            // ---- G2: zA -> z2 into zB ----
            {
                const uint32_t* zp = zAu + kh * 32;
                float a = 0.f, d = 0.f;
                #pragma unroll
                for (int q = 0; q < 8; ++q) {
                    uint4 zz = *reinterpret_cast<const uint4*>(zp + 4 * q);
                    a = dot2f(w2[4 * q + 0], zz.x, a); d = dot2f(w2[4 * q + 1], zz.y, d);
                    a = dot2f(w2[4 * q + 2], zz.z, a); d = dot2f(w2[4 * q + 3], zz.w, d);
                }
                float z = fmaxf(bh1_r + psum2(a + d), 0.f);
                if (kh == 0) ((_Float16*)zBu)[c] = (_Float16)z;
            }
            __syncthreads();

            // ---- G3: zB -> z3 into zA ----
            {
                const uint32_t* zp = zBu + kh * 32;
                float a = 0.f, d = 0.f;
                #pragma unroll
                for (int q = 0; q < 8; ++q) {
                    uint4 zz = *reinterpret_cast<const uint4*>(zp + 4 * q);
                    a = dot2f(w3[4 * q + 0], zz.x, a); d = dot2f(w3[4 * q + 1], zz.y, d);
                    a = dot2f(w3[4 * q + 2], zz.z, a); d = dot2f(w3[4 * q + 3], zz.w, d);
                }
                float z = fmaxf(bh2_r + psum2(a + d), 0.f);
                if (kh == 0) ((_Float16*)zAu)[c] = (_Float16)z;
            }
            __syncthreads();

            // ---- G4: z3 -> 384 cols, tanh, * dX ----
            {
                const uint32_t* zp = zAu + kh * 32;
                float a0 = 0.f, a1 = 0.f, a2 = 0.f;
                #pragma unroll
                for (int q = 0; q < 8; ++q) {
                    uint4 zz = *reinterpret_cast<const uint4*>(zp + 4 * q);
                    #pragma unroll
                    for (int i = 0; i < 4; ++i) {
                        uint32_t zi = (&zz.x)[i];
                        a0 = dot2f(w4[4 * q + i],      zi, a0);
                        a1 = dot2f(w4[32 + 4 * q + i], zi, a1);
                        a2 = dot2f(w4[64 + 4 * q + i], zi, a2);
                    }
                }
                a0 = psum2(a0);
                a1 = psum2(a1);
                a2 = psum2(a2);
                if (kh == 0) {
                    pp[c]       = tanh_fast(bo0 + a0) * dxs[m0];
                    pp[c + 128] = tanh_fast(bo1 + a1) * dxs[m1];
                    pp[c + 256] = tanh_fast(bo2 + a2) * dxs[m2];
                }
            }
            __syncthreads();

            // ---- k = A @ dX; RK4 bookkeeping; next vf input (wave 0) ----
            if (t < H_) {
                const float* pr = &pp[t * 6];
                float kv = pr[0] + pr[1] + pr[2] + pr[3] + pr[4] + pr[5];
                hacc += ((s4 == 1 || s4 == 2) ? 2.0f : 1.0f) * kv;
                float hs;
                if (s4 < 3) {
                    hs = h_reg + ((s4 == 2) ? 1.0f : 0.5f) * kv;
                } else {
                    h_reg += hacc * (1.0f / 6.0f);
                    hacc = 0.f;
                    hbuf[t] = h_reg;
                    hs = h_reg;
                }
                ((_Float16*)hinu)[t] = (_Float16)hs;
            }
            __syncthreads();
        }

        // ---- out for tt = step+1 (wave 0) ----
        if (t < 64) {
            int o = t & 7, part = t >> 3;
            float s = 0.f;
            #pragma unroll
            for (int j = 0; j < 8; ++j) s += hbuf[part * 8 + j] * wfr[j];
            s += __shfl_xor(s, 8);
            s += __shfl_xor(s, 16);
            s += __shfl_xor(s, 32);
            if (part == 0) out[obase + (size_t)(step + 1) * OUT_ + o] = s + bfin_r;
        }
    }
}

} // namespace

extern "C" void kernel_launch(void* const* d_in, const int* in_sizes, int n_in,
                              void* d_out, int out_size, void* d_ws, size_t ws_size,
                              hipStream_t stream) {
    const float* x      = (const float*)d_in[0];
    const float* W_init = (const float*)d_in[1];
    const float* b_init = (const float*)d_in[2];
    const float* W_in   = (const float*)d_in[3];
    const float* b_in   = (const float*)d_in[4];
    const float* W_h1   = (const float*)d_in[5];
    const float* b_h1   = (const float*)d_in[6];
    const float* W_h2   = (const float*)d_in[7];
    const float* b_h2   = (const float*)d_in[8];
    const float* W_out  = (const float*)d_in[9];
    const float* b_out  = (const float*)d_in[10];
    const float* W_fin  = (const float*)d_in[11];
    const float* b_fin  = (const float*)d_in[12];
    float* out = (float*)d_out;

    cde_kernel<<<dim3(B_), dim3(256), 0, stream>>>(
        x, W_init, b_init, W_in, b_in, W_h1, b_h1, W_h2, b_h2,
        W_out, b_out, W_fin, b_fin, out);
}